// Round 9
// baseline (194.154 us; speedup 1.0000x reference)
//
#include <hip/hip_runtime.h>

typedef __attribute__((ext_vector_type(4))) float f32x4;
typedef __attribute__((ext_vector_type(16))) float f32x16;
typedef __attribute__((ext_vector_type(8))) __bf16 bf16x8;
typedef __attribute__((ext_vector_type(4))) unsigned short u16x4;
typedef __attribute__((ext_vector_type(2))) unsigned int u32x2;

#define DEVI static __device__ __forceinline__

DEVI unsigned short bf16_bits(float f) {
  __bf16 h = (__bf16)f;
  return __builtin_bit_cast(unsigned short, h);
}

DEVI void gl_lds16(const void* g, void* l) {
  __builtin_amdgcn_global_load_lds(
      (const __attribute__((address_space(1))) void*)g,
      (__attribute__((address_space(3))) void*)l, 16, 0, 0);
}

DEVI f32x4 mfma16x16(bf16x8 a, bf16x8 b, f32x4 c) {
  return __builtin_amdgcn_mfma_f32_16x16x32_bf16(a, b, c, 0, 0, 0);
}

DEVI f32x16 mfma32(bf16x8 a, bf16x8 b, f32x16 c) {
  return __builtin_amdgcn_mfma_f32_32x32x16_bf16(a, b, c, 0, 0, 0);
}

DEVI unsigned cvtpk_bf16(float lo, float hi2) {
  unsigned r;
  asm("v_cvt_pk_bf16_f32 %0, %1, %2" : "=v"(r) : "v"(lo), "v"(hi2));
  return r;
}

// NOTE (r3/r4 lesson): never call with two copies of the same value — the
// allocator may coalesce them into ONE register and the swap degenerates.
// Only used with distinct values (P-pack). s_nop armor kept (verified r5-r8).
DEVI void pl32swap(unsigned& a, unsigned& b) {
  asm volatile("s_nop 1\nv_permlane32_swap_b32 %0, %1\ns_nop 1"
               : "+v"(a), "+v"(b));
}

// ---------------------------------------------------------------- LayerNorm
__global__ __launch_bounds__(256) void ln_kernel(
    const float* __restrict__ x, const float* __restrict__ gamma,
    const float* __restrict__ beta, __bf16* __restrict__ xn) {
  int row = blockIdx.x;
  int t = threadIdx.x;
  float4 v = ((const float4*)(x + (size_t)row * 1024))[t];
  float s = v.x + v.y + v.z + v.w;
  float sq = v.x * v.x + v.y * v.y + v.z * v.z + v.w * v.w;
#pragma unroll
  for (int off = 32; off > 0; off >>= 1) {
    s += __shfl_down(s, off);
    sq += __shfl_down(sq, off);
  }
  __shared__ float red[8];
  int w = t >> 6, ln = t & 63;
  if (ln == 0) { red[w] = s; red[4 + w] = sq; }
  __syncthreads();
  s = red[0] + red[1] + red[2] + red[3];
  sq = red[4] + red[5] + red[6] + red[7];
  float mu = s * (1.0f / 1024.0f);
  float var = sq * (1.0f / 1024.0f) - mu * mu;
  float rstd = rsqrtf(var + 1e-5f);
  float4 g = ((const float4*)gamma)[t];
  float4 b = ((const float4*)beta)[t];
  u16x4 o;
  o[0] = bf16_bits((v.x - mu) * rstd * g.x + b.x);
  o[1] = bf16_bits((v.y - mu) * rstd * g.y + b.y);
  o[2] = bf16_bits((v.z - mu) * rstd * g.z + b.z);
  o[3] = bf16_bits((v.w - mu) * rstd * g.w + b.w);
  *(u16x4*)(xn + (size_t)row * 1024 + t * 4) = o;
}

// -------------------------------------------- transpose fp32 [R][C] -> bf16 [C][R]
__global__ __launch_bounds__(256) void transpose_bf16_kernel(
    const float* __restrict__ in, __bf16* __restrict__ out, int R, int C) {
  __shared__ float tile[64][65];
  int tx = threadIdx.x & 15, ty = threadIdx.x >> 4;
  int c0 = blockIdx.x * 64, r0 = blockIdx.y * 64;
#pragma unroll
  for (int p = 0; p < 4; ++p) {
    int r = ty + p * 16;
    float4 v = *(const float4*)(in + (size_t)(r0 + r) * C + c0 + tx * 4);
    tile[r][tx * 4 + 0] = v.x;
    tile[r][tx * 4 + 1] = v.y;
    tile[r][tx * 4 + 2] = v.z;
    tile[r][tx * 4 + 3] = v.w;
  }
  __syncthreads();
#pragma unroll
  for (int p = 0; p < 4; ++p) {
    int cc = ty + p * 16;
    u16x4 o;
    o[0] = bf16_bits(tile[tx * 4 + 0][cc]);
    o[1] = bf16_bits(tile[tx * 4 + 1][cc]);
    o[2] = bf16_bits(tile[tx * 4 + 2][cc]);
    o[3] = bf16_bits(tile[tx * 4 + 3][cc]);
    *(u16x4*)(out + (size_t)(c0 + cc) * R + r0 + tx * 4) = o;
  }
}

// ---------------------------------------------------------------- GEMM
template <int EPI>
__global__ __launch_bounds__(256) void gemm_kernel(
    const __bf16* __restrict__ A, const __bf16* __restrict__ BT,
    float* __restrict__ Cout, const float* __restrict__ bias,
    __bf16* __restrict__ Qb, __bf16* __restrict__ Kb, __bf16* __restrict__ VTb) {
  __shared__ __align__(16) __bf16 Asm[128 * 32];
  __shared__ __align__(16) __bf16 Bsm[128 * 32];
  const int KD = 1024;
  int t = threadIdx.x;
  int w = t >> 6, ln = t & 63;
  int wr = w >> 1, wc = w & 1;
  int m0 = blockIdx.y * 128, n0 = blockIdx.x * 128;
  f32x4 acc[4][4] = {};

  int srow = w * 16 + (ln >> 2);
  int scol = (ln & 3) * 8;
  int lrow = ln & 15;
  int lkb = (ln >> 4) * 16;

  for (int kk = 0; kk < KD; kk += 32) {
    __syncthreads();
#pragma unroll
    for (int i = 0; i < 2; ++i) {
      int row = i * 64 + srow;
      gl_lds16(A + (size_t)(m0 + row) * KD + kk + scol,
               (char*)Asm + i * 4096 + w * 1024);
      gl_lds16(BT + (size_t)(n0 + row) * KD + kk + scol,
               (char*)Bsm + i * 4096 + w * 1024);
    }
    __syncthreads();
    bf16x8 af[4], bfr[4];
#pragma unroll
    for (int mi = 0; mi < 4; ++mi)
      af[mi] = *(const bf16x8*)((char*)Asm + (wr * 64 + mi * 16 + lrow) * 64 + lkb);
#pragma unroll
    for (int ni = 0; ni < 4; ++ni)
      bfr[ni] = *(const bf16x8*)((char*)Bsm + (wc * 64 + ni * 16 + lrow) * 64 + lkb);
#pragma unroll
    for (int mi = 0; mi < 4; ++mi)
#pragma unroll
      for (int ni = 0; ni < 4; ++ni)
        acc[mi][ni] = mfma16x16(af[mi], bfr[ni], acc[mi][ni]);
  }

  int r4 = (ln >> 4) * 4;
#pragma unroll
  for (int mi = 0; mi < 4; ++mi) {
#pragma unroll
    for (int ni = 0; ni < 4; ++ni) {
      int grow = m0 + wr * 64 + mi * 16 + r4;
      int gcol = n0 + wc * 64 + ni * 16 + lrow;
      if (EPI == 0) {
        int sel = gcol >> 10;
        int nl = gcol & 1023;
        int h = nl >> 6, d = nl & 63;
        int b = grow >> 11, seq = grow & 2047;
        int bh = b * 16 + h;
        if (sel < 2) {
          __bf16* dst = (sel == 0 ? Qb : Kb) + ((size_t)bh * 2048 + seq) * 64 + d;
#pragma unroll
          for (int r = 0; r < 4; ++r) dst[(size_t)r * 64] = (__bf16)acc[mi][ni][r];
        } else {
          u16x4 o;
          o[0] = bf16_bits(acc[mi][ni][0]);
          o[1] = bf16_bits(acc[mi][ni][1]);
          o[2] = bf16_bits(acc[mi][ni][2]);
          o[3] = bf16_bits(acc[mi][ni][3]);
          *(u16x4*)(VTb + ((size_t)bh * 64 + d) * 2048 + seq) = o;
        }
      } else {
        float bv = bias[gcol];
#pragma unroll
        for (int r = 0; r < 4; ++r)
          Cout[(size_t)(grow + r) * 1024 + gcol] = acc[mi][ni][r] + bv;
      }
    }
  }
}

// ---------------------------------------------------------------- attention
// Round-9: NO LDS staging, NO barriers. K/V fragments read directly from
// global (L2-resident: K+V = 512KB/head, ~4 heads per XCD L2). Deletes the
// structural ds_read bank conflicts (4.26M, constant r2-r8) and the barrier
// lockstep; waves fully independent. 4 waves x 32 q-rows; no-max softmax
// (r8-verified); per-wave epilogue scratch (no barrier needed).
__global__ __launch_bounds__(256) void attn_kernel(
    const __bf16* __restrict__ Qb, const __bf16* __restrict__ Kb,
    const __bf16* __restrict__ VTb, __bf16* __restrict__ sa) {
  __shared__ __align__(16) char Ow4[16384];  // 4 waves x 4KB transpose scratch
  const float LOG2E = 1.44269504f;
  const float K1 = 0.125f * LOG2E;
  int t = threadIdx.x, w = t >> 6, ln = t & 63;
  int hi = ln >> 5, col = ln & 31;
  int bh = blockIdx.y, bq = bh >> 4, h = bh & 15;
  int q0 = blockIdx.x * 128;
  const __bf16* Qh = Qb + (size_t)bh * 2048 * 64;
  const __bf16* Kh = Kb + (size_t)bh * 2048 * 64;
  const __bf16* Vh = VTb + (size_t)bh * 64 * 2048;

  // Q B-frags: lane: i = col, d = dk*16 + hi*8 + 0..7
  bf16x8 qf[4];
  int qrow = q0 + w * 32 + col;
#pragma unroll
  for (int dk = 0; dk < 4; ++dk)
    qf[dk] = *(const bf16x8*)(Qh + (size_t)qrow * 64 + dk * 16 + hi * 8);

  f32x16 oacc0 = {}, oacc1 = {};
  float l_run = 0.f;

  const __bf16* Krow0 = Kh + (size_t)col * 64 + hi * 8;        // row col
  const __bf16* Krow1 = Kh + (size_t)(32 + col) * 64 + hi * 8; // row 32+col
  const __bf16* Vrow0 = Vh + (size_t)col * 2048 + hi * 8;      // d=col
  const __bf16* Vrow1 = Vh + (size_t)(32 + col) * 2048 + hi * 8;

#pragma unroll 2
  for (int jt = 0; jt < 32; ++jt) {
    int j0 = jt * 64;

    // QK^T: sfr[s] = S^T[j = 32s + crow(r,hi)][i = col]; K direct from L2.
    f32x16 sfr0 = {}, sfr1 = {};
#pragma unroll
    for (int dk = 0; dk < 4; ++dk) {
      bf16x8 kf0 = *(const bf16x8*)(Krow0 + (size_t)j0 * 64 + dk * 16);
      bf16x8 kf1 = *(const bf16x8*)(Krow1 + (size_t)j0 * 64 + dk * 16);
      sfr0 = mfma32(kf0, qf[dk], sfr0);
      sfr1 = mfma32(kf1, qf[dk], sfr1);
    }

    // no-max softmax: p = exp2(S*K1); l per-lane, one exchange after loop.
    float psum = 0.f;
    bf16x8 pfr[4];
#pragma unroll
    for (int jk = 0; jk < 4; ++jk) {
      float p[8];
#pragma unroll
      for (int c = 0; c < 8; ++c) {
        float sv = (jk < 2) ? sfr0[(jk & 1) * 8 + c] : sfr1[(jk & 1) * 8 + c];
        p[c] = __builtin_amdgcn_exp2f(sv * K1);
      }
      psum += ((p[0] + p[1]) + (p[2] + p[3])) + ((p[4] + p[5]) + (p[6] + p[7]));
      unsigned X0 = cvtpk_bf16(p[0], p[1]);
      unsigned X1 = cvtpk_bf16(p[2], p[3]);
      unsigned Y0 = cvtpk_bf16(p[4], p[5]);
      unsigned Y1 = cvtpk_bf16(p[6], p[7]);
      pl32swap(X0, Y0);
      pl32swap(X1, Y1);
      union { unsigned u[4]; bf16x8 v; } pu;
      pu.u[0] = X0; pu.u[1] = X1; pu.u[2] = Y0; pu.u[3] = Y1;
      pfr[jk] = pu.v;
    }
    l_run += psum;

    // PV: O^T[d][i] += V^T[d][j] P^T[j][i]; V direct from L2.
#pragma unroll
    for (int jk = 0; jk < 4; ++jk) {
      bf16x8 vf0 = *(const bf16x8*)(Vrow0 + j0 + jk * 16);
      bf16x8 vf1 = *(const bf16x8*)(Vrow1 + j0 + jk * 16);
      oacc0 = mfma32(vf0, pfr[jk], oacc0);
      oacc1 = mfma32(vf1, pfr[jk], oacc1);
    }
  }

  // single cross-half l exchange (partner lane holds the other 32 j's)
  l_run += __shfl_xor(l_run, 32);
  float linv = 1.0f / l_run;

  // epilogue: normalize, transpose O^T -> O via per-wave LDS (exclusive
  // region -> no barrier), coalesced 16B stores.
  char* Ow = Ow4 + w * 4096;  // [32 i][128B d-row], swizzled
#pragma unroll
  for (int da = 0; da < 2; ++da) {
    const f32x16& oa = da ? oacc1 : oacc0;
#pragma unroll
    for (int g = 0; g < 4; ++g) {
      unsigned w0 = cvtpk_bf16(oa[g * 4 + 0] * linv, oa[g * 4 + 1] * linv);
      unsigned w1 = cvtpk_bf16(oa[g * 4 + 2] * linv, oa[g * 4 + 3] * linv);
      int dby = da * 64 + g * 16 + hi * 8;
      char* dst = Ow + col * 128 + ((dby & ~15) ^ ((col & 7) << 4)) + (dby & 8);
      u32x2 pr = {w0, w1};
      *(u32x2*)dst = pr;
    }
  }
  int rr0 = ln >> 3, c16o = ln & 7;
#pragma unroll
  for (int pp = 0; pp < 4; ++pp) {
    int rr = rr0 + pp * 8;
    bf16x8 ov = *(const bf16x8*)(Ow + rr * 128 + ((c16o * 16) ^ ((rr & 7) << 4)));
    int grow = bq * 2048 + q0 + w * 32 + rr;
    *(bf16x8*)(sa + (size_t)grow * 1024 + h * 64 + c16o * 8) = ov;
  }
}

// ---------------------------------------------------------------- launch
extern "C" void kernel_launch(void* const* d_in, const int* in_sizes, int n_in,
                              void* d_out, int out_size, void* d_ws, size_t ws_size,
                              hipStream_t stream) {
  const float* x = (const float*)d_in[0];
  const float* gamma = (const float*)d_in[1];
  const float* beta = (const float*)d_in[2];
  const float* w_qkv = (const float*)d_in[3];
  const float* w_out = (const float*)d_in[4];
  const float* b_out = (const float*)d_in[5];

  char* ws = (char*)d_ws;
  __bf16* xn = (__bf16*)(ws);                       // 8 MB (reused as sa)
  __bf16* wqkvT = (__bf16*)(ws + (8l << 20));       // 6 MB
  __bf16* woutT = (__bf16*)(ws + (14l << 20));      // 2 MB
  __bf16* Qb = (__bf16*)(ws + (16l << 20));         // 8 MB
  __bf16* Kb = (__bf16*)(ws + (24l << 20));         // 8 MB
  __bf16* VTb = (__bf16*)(ws + (32l << 20));        // 8 MB
  __bf16* sa = xn;                                  // xn dead after QKV GEMM

  ln_kernel<<<4096, 256, 0, stream>>>(x, gamma, beta, xn);
  transpose_bf16_kernel<<<dim3(48, 16), 256, 0, stream>>>(w_qkv, wqkvT, 1024, 3072);
  transpose_bf16_kernel<<<dim3(16, 16), 256, 0, stream>>>(w_out, woutT, 1024, 1024);
  gemm_kernel<0><<<dim3(24, 32), 256, 0, stream>>>(xn, wqkvT, nullptr, nullptr,
                                                   Qb, Kb, VTb);
  attn_kernel<<<dim3(16, 32), 256, 0, stream>>>(Qb, Kb, VTb, sa);
  gemm_kernel<1><<<dim3(8, 32), 256, 0, stream>>>(sa, woutT, (float*)d_out, b_out,
                                                  nullptr, nullptr, nullptr);
}

// Round 11
// 127.676 us; speedup vs baseline: 1.5207x; 1.5207x over previous
//
#include <hip/hip_runtime.h>

typedef __attribute__((ext_vector_type(4))) float f32x4;
typedef __attribute__((ext_vector_type(16))) float f32x16;
typedef __attribute__((ext_vector_type(8))) __bf16 bf16x8;
typedef __attribute__((ext_vector_type(4))) unsigned short u16x4;
typedef __attribute__((ext_vector_type(2))) unsigned int u32x2;

#define DEVI static __device__ __forceinline__

DEVI unsigned short bf16_bits(float f) {
  __bf16 h = (__bf16)f;
  return __builtin_bit_cast(unsigned short, h);
}

DEVI float bf16_f32(unsigned short u) {
  return (float)__builtin_bit_cast(__bf16, u);
}

DEVI void gl_lds16(const void* g, void* l) {
  __builtin_amdgcn_global_load_lds(
      (const __attribute__((address_space(1))) void*)g,
      (__attribute__((address_space(3))) void*)l, 16, 0, 0);
}

DEVI f32x4 mfma16x16(bf16x8 a, bf16x8 b, f32x4 c) {
  return __builtin_amdgcn_mfma_f32_16x16x32_bf16(a, b, c, 0, 0, 0);
}

DEVI f32x16 mfma32(bf16x8 a, bf16x8 b, f32x16 c) {
  return __builtin_amdgcn_mfma_f32_32x32x16_bf16(a, b, c, 0, 0, 0);
}

DEVI unsigned cvtpk_bf16(float lo, float hi2) {
  unsigned r;
  asm("v_cvt_pk_bf16_f32 %0, %1, %2" : "=v"(r) : "v"(lo), "v"(hi2));
  return r;
}

// NOTE (r3/r4 lesson): never call with two copies of the same value — the
// allocator may coalesce them into ONE register and the swap degenerates.
DEVI void pl32swap(unsigned& a, unsigned& b) {
  asm volatile("s_nop 1\nv_permlane32_swap_b32 %0, %1\ns_nop 1"
               : "+v"(a), "+v"(b));
}

#define WAITVM0 asm volatile("s_waitcnt vmcnt(0)" ::: "memory")

// ---------------------------------------------------------------- LayerNorm
__global__ __launch_bounds__(256) void ln_kernel(
    const float* __restrict__ x, const float* __restrict__ gamma,
    const float* __restrict__ beta, __bf16* __restrict__ xn) {
  int row = blockIdx.x;
  int t = threadIdx.x;
  float4 v = ((const float4*)(x + (size_t)row * 1024))[t];
  float s = v.x + v.y + v.z + v.w;
  float sq = v.x * v.x + v.y * v.y + v.z * v.z + v.w * v.w;
#pragma unroll
  for (int off = 32; off > 0; off >>= 1) {
    s += __shfl_down(s, off);
    sq += __shfl_down(sq, off);
  }
  __shared__ float red[8];
  int w = t >> 6, ln = t & 63;
  if (ln == 0) { red[w] = s; red[4 + w] = sq; }
  __syncthreads();
  s = red[0] + red[1] + red[2] + red[3];
  sq = red[4] + red[5] + red[6] + red[7];
  float mu = s * (1.0f / 1024.0f);
  float var = sq * (1.0f / 1024.0f) - mu * mu;
  float rstd = rsqrtf(var + 1e-5f);
  float4 g = ((const float4*)gamma)[t];
  float4 b = ((const float4*)beta)[t];
  u16x4 o;
  o[0] = bf16_bits((v.x - mu) * rstd * g.x + b.x);
  o[1] = bf16_bits((v.y - mu) * rstd * g.y + b.y);
  o[2] = bf16_bits((v.z - mu) * rstd * g.z + b.z);
  o[3] = bf16_bits((v.w - mu) * rstd * g.w + b.w);
  *(u16x4*)(xn + (size_t)row * 1024 + t * 4) = o;
}

// -------------------------------------------- transpose fp32 [R][C] -> bf16 [C][R]
__global__ __launch_bounds__(256) void transpose_bf16_kernel(
    const float* __restrict__ in, __bf16* __restrict__ out, int R, int C) {
  __shared__ float tile[64][65];
  int tx = threadIdx.x & 15, ty = threadIdx.x >> 4;
  int c0 = blockIdx.x * 64, r0 = blockIdx.y * 64;
#pragma unroll
  for (int p = 0; p < 4; ++p) {
    int r = ty + p * 16;
    float4 v = *(const float4*)(in + (size_t)(r0 + r) * C + c0 + tx * 4);
    tile[r][tx * 4 + 0] = v.x;
    tile[r][tx * 4 + 1] = v.y;
    tile[r][tx * 4 + 2] = v.z;
    tile[r][tx * 4 + 3] = v.w;
  }
  __syncthreads();
#pragma unroll
  for (int p = 0; p < 4; ++p) {
    int cc = ty + p * 16;
    u16x4 o;
    o[0] = bf16_bits(tile[tx * 4 + 0][cc]);
    o[1] = bf16_bits(tile[tx * 4 + 1][cc]);
    o[2] = bf16_bits(tile[tx * 4 + 2][cc]);
    o[3] = bf16_bits(tile[tx * 4 + 3][cc]);
    *(u16x4*)(out + (size_t)(c0 + cc) * R + r0 + tx * 4) = o;
  }
}

// ---------------------------------------------------------------- GEMM
template <int EPI>
__global__ __launch_bounds__(256) void gemm_kernel(
    const __bf16* __restrict__ A, const __bf16* __restrict__ BT,
    float* __restrict__ Cout, const float* __restrict__ bias,
    __bf16* __restrict__ Qb, __bf16* __restrict__ Kb, __bf16* __restrict__ VTb) {
  __shared__ __align__(16) __bf16 Asm[128 * 32];
  __shared__ __align__(16) __bf16 Bsm[128 * 32];
  const int KD = 1024;
  int t = threadIdx.x;
  int w = t >> 6, ln = t & 63;
  int wr = w >> 1, wc = w & 1;
  int m0 = blockIdx.y * 128, n0 = blockIdx.x * 128;
  f32x4 acc[4][4] = {};

  int srow = w * 16 + (ln >> 2);
  int scol = (ln & 3) * 8;
  int lrow = ln & 15;
  int lkb = (ln >> 4) * 16;

  for (int kk = 0; kk < KD; kk += 32) {
    __syncthreads();
#pragma unroll
    for (int i = 0; i < 2; ++i) {
      int row = i * 64 + srow;
      gl_lds16(A + (size_t)(m0 + row) * KD + kk + scol,
               (char*)Asm + i * 4096 + w * 1024);
      gl_lds16(BT + (size_t)(n0 + row) * KD + kk + scol,
               (char*)Bsm + i * 4096 + w * 1024);
    }
    __syncthreads();
    bf16x8 af[4], bfr[4];
#pragma unroll
    for (int mi = 0; mi < 4; ++mi)
      af[mi] = *(const bf16x8*)((char*)Asm + (wr * 64 + mi * 16 + lrow) * 64 + lkb);
#pragma unroll
    for (int ni = 0; ni < 4; ++ni)
      bfr[ni] = *(const bf16x8*)((char*)Bsm + (wc * 64 + ni * 16 + lrow) * 64 + lkb);
#pragma unroll
    for (int mi = 0; mi < 4; ++mi)
#pragma unroll
      for (int ni = 0; ni < 4; ++ni)
        acc[mi][ni] = mfma16x16(af[mi], bfr[ni], acc[mi][ni]);
  }

  int r4 = (ln >> 4) * 4;
#pragma unroll
  for (int mi = 0; mi < 4; ++mi) {
#pragma unroll
    for (int ni = 0; ni < 4; ++ni) {
      int grow = m0 + wr * 64 + mi * 16 + r4;
      int gcol = n0 + wc * 64 + ni * 16 + lrow;
      if (EPI == 0) {
        int sel = gcol >> 10;
        int nl = gcol & 1023;
        int h = nl >> 6, d = nl & 63;
        int b = grow >> 11, seq = grow & 2047;
        int bh = b * 16 + h;
        if (sel < 2) {
          __bf16* dst = (sel == 0 ? Qb : Kb) + ((size_t)bh * 2048 + seq) * 64 + d;
#pragma unroll
          for (int r = 0; r < 4; ++r) dst[(size_t)r * 64] = (__bf16)acc[mi][ni][r];
        } else {
          u16x4 o;
          o[0] = bf16_bits(acc[mi][ni][0]);
          o[1] = bf16_bits(acc[mi][ni][1]);
          o[2] = bf16_bits(acc[mi][ni][2]);
          o[3] = bf16_bits(acc[mi][ni][3]);
          *(u16x4*)(VTb + ((size_t)bh * 64 + d) * 2048 + seq) = o;
        }
      } else {
        float bv = bias[gcol];
#pragma unroll
        for (int r = 0; r < 4; ++r)
          Cout[(size_t)(grow + r) * 1024 + gcol] = acc[mi][ni][r] + bv;
      }
    }
  }
}

// ---------------------------------------------------------------- attention
// Round-11: j-SPLIT flash (exact under no-max softmax — partials are linear).
// Grid (16 qb, 32 bh, 2 jh) = 1024 blocks = 4/CU = 16 waves/CU (2x hiding).
// r10 bug fixed: half-buffer stride is 4096*1024 elements (8MB), was 16MB
// and clobbered lbuf + woutT -> NaN.
__global__ __launch_bounds__(256, 2) void attn_kernel(
    const __bf16* __restrict__ Qb, const __bf16* __restrict__ Kb,
    const __bf16* __restrict__ VTb, __bf16* __restrict__ Opart,
    float* __restrict__ lbuf) {
  __shared__ __align__(16) char Klds[16384];   // 2 bufs x [64 j][128B], swizzled
  __shared__ __align__(16) char Vlds[16384];   // 2 bufs x [64 d][128B], swizzled
  const float LOG2E = 1.44269504f;
  const float K1 = 0.125f * LOG2E;
  int t = threadIdx.x, w = t >> 6, ln = t & 63;
  int hi = ln >> 5, col = ln & 31;
  int bh = blockIdx.y, bq = bh >> 4, h = bh & 15;
  int q0 = blockIdx.x * 128;
  int jh = blockIdx.z;                 // j-half: tiles jh*16 .. jh*16+15
  const __bf16* Qh = Qb + (size_t)bh * 2048 * 64;
  const __bf16* Kh = Kb + (size_t)bh * 2048 * 64;
  const __bf16* Vh = VTb + (size_t)bh * 64 * 2048;
  __bf16* Oh = Opart + (size_t)jh * 4096 * 1024;  // half = 4M bf16 = 8MB (FIX)

  // Q B-frags: lane: i = col, d = dk*16 + hi*8 + 0..7
  bf16x8 qf[4];
  int qrow = q0 + w * 32 + col;
#pragma unroll
  for (int dk = 0; dk < 4; ++dk)
    qf[dk] = *(const bf16x8*)(Qh + (size_t)qrow * 64 + dk * 16 + hi * 8);

  f32x16 oacc0 = {}, oacc1 = {};
  float l_run = 0.f;

  // staging: thread covers phys bytes t*16 and t*16+4096 of an 8KB tile.
  int sj0 = t >> 3, sc0 = (t & 7) ^ (sj0 & 7);
  int sj1 = 32 + (t >> 3), sc1 = (t & 7) ^ (sj1 & 7);

#define STAGE(off, j0_)                                                        \
  do {                                                                         \
    gl_lds16(Kh + (size_t)((j0_) + sj0) * 64 + sc0 * 8, Klds + (off) + w * 1024); \
    gl_lds16(Kh + (size_t)((j0_) + sj1) * 64 + sc1 * 8,                        \
             Klds + (off) + 4096 + w * 1024);                                  \
    gl_lds16(Vh + (size_t)sj0 * 2048 + (j0_) + sc0 * 8, Vlds + (off) + w * 1024); \
    gl_lds16(Vh + (size_t)sj1 * 2048 + (j0_) + sc1 * 8,                        \
             Vlds + (off) + 4096 + w * 1024);                                  \
  } while (0)

  int jbase = jh * 16;
  int cur = 0;
  STAGE(0, jbase * 64);
  WAITVM0;
  __builtin_amdgcn_s_barrier();
  __builtin_amdgcn_sched_barrier(0);

  for (int jt = 0; jt < 16; ++jt) {
    if (jt < 15) STAGE((cur ^ 1) * 8192, (jbase + jt + 1) * 64);
    const char* Kc = Klds + cur * 8192;
    const char* Vc = Vlds + cur * 8192;

    // QK^T: sfr[s] = S^T[j = 32s + crow(r,hi)][i = col]
    f32x16 sfr0 = {}, sfr1 = {};
#pragma unroll
    for (int dk = 0; dk < 4; ++dk) {
      int sw = ((dk * 32 + hi * 16) ^ ((col & 7) << 4));
      bf16x8 kf0 = *(const bf16x8*)(Kc + col * 128 + sw);
      bf16x8 kf1 = *(const bf16x8*)(Kc + (32 + col) * 128 + sw);
      sfr0 = mfma32(kf0, qf[dk], sfr0);
      sfr1 = mfma32(kf1, qf[dk], sfr1);
    }

    // no-max softmax: p = exp2(S*K1); l per-lane, one exchange after loop.
    float psum = 0.f;
    bf16x8 pfr[4];
#pragma unroll
    for (int jk = 0; jk < 4; ++jk) {
      float p[8];
#pragma unroll
      for (int c = 0; c < 8; ++c) {
        float sv = (jk < 2) ? sfr0[(jk & 1) * 8 + c] : sfr1[(jk & 1) * 8 + c];
        p[c] = __builtin_amdgcn_exp2f(sv * K1);
      }
      psum += ((p[0] + p[1]) + (p[2] + p[3])) + ((p[4] + p[5]) + (p[6] + p[7]));
      unsigned X0 = cvtpk_bf16(p[0], p[1]);
      unsigned X1 = cvtpk_bf16(p[2], p[3]);
      unsigned Y0 = cvtpk_bf16(p[4], p[5]);
      unsigned Y1 = cvtpk_bf16(p[6], p[7]);
      pl32swap(X0, Y0);
      pl32swap(X1, Y1);
      union { unsigned u[4]; bf16x8 v; } pu;
      pu.u[0] = X0; pu.u[1] = X1; pu.u[2] = Y0; pu.u[3] = Y1;
      pfr[jk] = pu.v;
    }
    l_run += psum;

    // PV: O^T[d][i] += V^T[d][j] P^T[j][i]
#pragma unroll
    for (int jk = 0; jk < 4; ++jk) {
      int sw = ((jk * 32 + hi * 16) ^ ((col & 7) << 4));
      bf16x8 vf0 = *(const bf16x8*)(Vc + col * 128 + sw);
      bf16x8 vf1 = *(const bf16x8*)(Vc + (32 + col) * 128 + sw);
      oacc0 = mfma32(vf0, pfr[jk], oacc0);
      oacc1 = mfma32(vf1, pfr[jk], oacc1);
    }

    WAITVM0;
    __builtin_amdgcn_s_barrier();
    __builtin_amdgcn_sched_barrier(0);
    cur ^= 1;
  }
#undef STAGE

  // single cross-half l exchange (partner lane holds the other 32 j's)
  l_run += __shfl_xor(l_run, 32);
  float linv = 1.0f / l_run;
  // store l for combine (lane i = col; hi==0 lanes cover i = w*32 + col)
  if (hi == 0)
    lbuf[(((size_t)bh * 16 + blockIdx.x) * 2 + jh) * 128 + w * 32 + col] = l_run;

  // epilogue: normalize, transpose O^T -> O via per-wave LDS, coalesced store
  char* Ow = Klds + w * 4096;  // [32 i][128B d-row], swizzled
#pragma unroll
  for (int da = 0; da < 2; ++da) {
    const f32x16& oa = da ? oacc1 : oacc0;
#pragma unroll
    for (int g = 0; g < 4; ++g) {
      unsigned w0 = cvtpk_bf16(oa[g * 4 + 0] * linv, oa[g * 4 + 1] * linv);
      unsigned w1 = cvtpk_bf16(oa[g * 4 + 2] * linv, oa[g * 4 + 3] * linv);
      int dby = da * 64 + g * 16 + hi * 8;
      char* dst = Ow + col * 128 + ((dby & ~15) ^ ((col & 7) << 4)) + (dby & 8);
      u32x2 pr = {w0, w1};
      *(u32x2*)dst = pr;
    }
  }
  int rr0 = ln >> 3, c16o = ln & 7;
#pragma unroll
  for (int pp = 0; pp < 4; ++pp) {
    int rr = rr0 + pp * 8;
    bf16x8 ov = *(const bf16x8*)(Ow + rr * 128 + ((c16o * 16) ^ ((rr & 7) << 4)));
    int grow = bq * 2048 + q0 + w * 32 + rr;
    *(bf16x8*)(Oh + (size_t)grow * 1024 + h * 64 + c16o * 8) = ov;
  }
}

// ------------------------------------------------------------- combine
// sa[r][c] = (l0*O0n + l1*O1n)/(l0+l1); in-place over O0 (each thread touches
// only its own bytes). One block per row; thread t covers cols 4t..4t+3.
__global__ __launch_bounds__(256) void combine_kernel(
    __bf16* __restrict__ O0, const __bf16* __restrict__ O1,
    const float* __restrict__ lbuf) {
  int r = blockIdx.x, t = threadIdx.x;
  int b = r >> 11, seq = r & 2047, qb = seq >> 7, i = seq & 127;
  int c0 = t * 4, h = c0 >> 6;
  int bh = b * 16 + h;
  size_t lbase = (((size_t)bh * 16 + qb) * 2) * 128 + i;
  float l0 = lbuf[lbase], l1 = lbuf[lbase + 128];
  float inv = 1.0f / (l0 + l1);
  float w0 = l0 * inv, w1 = l1 * inv;
  u16x4 a = *(const u16x4*)(O0 + (size_t)r * 1024 + c0);
  u16x4 bb = *(const u16x4*)(O1 + (size_t)r * 1024 + c0);
  u16x4 o;
#pragma unroll
  for (int j = 0; j < 4; ++j)
    o[j] = bf16_bits(w0 * bf16_f32(a[j]) + w1 * bf16_f32(bb[j]));
  *(u16x4*)(O0 + (size_t)r * 1024 + c0) = o;
}

// ---------------------------------------------------------------- launch
extern "C" void kernel_launch(void* const* d_in, const int* in_sizes, int n_in,
                              void* d_out, int out_size, void* d_ws, size_t ws_size,
                              hipStream_t stream) {
  const float* x = (const float*)d_in[0];
  const float* gamma = (const float*)d_in[1];
  const float* beta = (const float*)d_in[2];
  const float* w_qkv = (const float*)d_in[3];
  const float* w_out = (const float*)d_in[4];
  const float* b_out = (const float*)d_in[5];

  char* ws = (char*)d_ws;
  // [0..8): xn / attn half-0 partial / final sa (in-place combine)
  // [8..16): attn half-1 partial
  // [16..22): wqkvT (dead after QKV GEMM; first 512KB reused as lbuf by attn)
  // [22..24): woutT
  // [24..32): Qb   [32..40): Kb   [40..48): VTb
  __bf16* xn = (__bf16*)(ws);
  __bf16* Opart = xn;                               // halves at +0MB / +8MB
  float* lbuf = (float*)(ws + (16l << 20));
  __bf16* wqkvT = (__bf16*)(ws + (16l << 20));
  __bf16* woutT = (__bf16*)(ws + (22l << 20));
  __bf16* Qb = (__bf16*)(ws + (24l << 20));
  __bf16* Kb = (__bf16*)(ws + (32l << 20));
  __bf16* VTb = (__bf16*)(ws + (40l << 20));
  __bf16* sa = xn;  // combine merges half-1 into half-0 in place

  ln_kernel<<<4096, 256, 0, stream>>>(x, gamma, beta, xn);
  transpose_bf16_kernel<<<dim3(48, 16), 256, 0, stream>>>(w_qkv, wqkvT, 1024, 3072);
  transpose_bf16_kernel<<<dim3(16, 16), 256, 0, stream>>>(w_out, woutT, 1024, 1024);
  gemm_kernel<0><<<dim3(24, 32), 256, 0, stream>>>(xn, wqkvT, nullptr, nullptr,
                                                   Qb, Kb, VTb);
  attn_kernel<<<dim3(16, 32, 2), 256, 0, stream>>>(Qb, Kb, VTb, Opart, lbuf);
  combine_kernel<<<4096, 256, 0, stream>>>(sa, Opart + (4096l * 1024), lbuf);
  gemm_kernel<1><<<dim3(8, 32), 256, 0, stream>>>(sa, woutT, (float*)d_out, b_out,
                                                  nullptr, nullptr, nullptr);
}

// Round 12
// 125.216 us; speedup vs baseline: 1.5506x; 1.0196x over previous
//
#include <hip/hip_runtime.h>

typedef __attribute__((ext_vector_type(4))) float f32x4;
typedef __attribute__((ext_vector_type(16))) float f32x16;
typedef __attribute__((ext_vector_type(8))) __bf16 bf16x8;
typedef __attribute__((ext_vector_type(4))) unsigned short u16x4;
typedef __attribute__((ext_vector_type(2))) unsigned int u32x2;

#define DEVI static __device__ __forceinline__

DEVI unsigned short bf16_bits(float f) {
  __bf16 h = (__bf16)f;
  return __builtin_bit_cast(unsigned short, h);
}

DEVI float bf16_f32(__bf16 u) { return (float)u; }

DEVI void gl_lds16(const void* g, void* l) {
  __builtin_amdgcn_global_load_lds(
      (const __attribute__((address_space(1))) void*)g,
      (__attribute__((address_space(3))) void*)l, 16, 0, 0);
}

DEVI f32x4 mfma16x16(bf16x8 a, bf16x8 b, f32x4 c) {
  return __builtin_amdgcn_mfma_f32_16x16x32_bf16(a, b, c, 0, 0, 0);
}

DEVI f32x16 mfma32(bf16x8 a, bf16x8 b, f32x16 c) {
  return __builtin_amdgcn_mfma_f32_32x32x16_bf16(a, b, c, 0, 0, 0);
}

DEVI unsigned cvtpk_bf16(float lo, float hi2) {
  unsigned r;
  asm("v_cvt_pk_bf16_f32 %0, %1, %2" : "=v"(r) : "v"(lo), "v"(hi2));
  return r;
}

// NOTE (r3/r4 lesson): never call with two copies of the same value — the
// allocator may coalesce them into ONE register and the swap degenerates.
DEVI void pl32swap(unsigned& a, unsigned& b) {
  asm volatile("s_nop 1\nv_permlane32_swap_b32 %0, %1\ns_nop 1"
               : "+v"(a), "+v"(b));
}

#define WAITVM0 asm volatile("s_waitcnt vmcnt(0)" ::: "memory")

// ---------------------------------------------------------------- LayerNorm
__global__ __launch_bounds__(256) void ln_kernel(
    const float* __restrict__ x, const float* __restrict__ gamma,
    const float* __restrict__ beta, __bf16* __restrict__ xn) {
  int row = blockIdx.x;
  int t = threadIdx.x;
  float4 v = ((const float4*)(x + (size_t)row * 1024))[t];
  float s = v.x + v.y + v.z + v.w;
  float sq = v.x * v.x + v.y * v.y + v.z * v.z + v.w * v.w;
#pragma unroll
  for (int off = 32; off > 0; off >>= 1) {
    s += __shfl_down(s, off);
    sq += __shfl_down(sq, off);
  }
  __shared__ float red[8];
  int w = t >> 6, ln = t & 63;
  if (ln == 0) { red[w] = s; red[4 + w] = sq; }
  __syncthreads();
  s = red[0] + red[1] + red[2] + red[3];
  sq = red[4] + red[5] + red[6] + red[7];
  float mu = s * (1.0f / 1024.0f);
  float var = sq * (1.0f / 1024.0f) - mu * mu;
  float rstd = rsqrtf(var + 1e-5f);
  float4 g = ((const float4*)gamma)[t];
  float4 b = ((const float4*)beta)[t];
  u16x4 o;
  o[0] = bf16_bits((v.x - mu) * rstd * g.x + b.x);
  o[1] = bf16_bits((v.y - mu) * rstd * g.y + b.y);
  o[2] = bf16_bits((v.z - mu) * rstd * g.z + b.z);
  o[3] = bf16_bits((v.w - mu) * rstd * g.w + b.w);
  *(u16x4*)(xn + (size_t)row * 1024 + t * 4) = o;
}

// -------------------------------------------- transpose fp32 [R][C] -> bf16 [C][R]
__global__ __launch_bounds__(256) void transpose_bf16_kernel(
    const float* __restrict__ in, __bf16* __restrict__ out, int R, int C) {
  __shared__ float tile[64][65];
  int tx = threadIdx.x & 15, ty = threadIdx.x >> 4;
  int c0 = blockIdx.x * 64, r0 = blockIdx.y * 64;
#pragma unroll
  for (int p = 0; p < 4; ++p) {
    int r = ty + p * 16;
    float4 v = *(const float4*)(in + (size_t)(r0 + r) * C + c0 + tx * 4);
    tile[r][tx * 4 + 0] = v.x;
    tile[r][tx * 4 + 1] = v.y;
    tile[r][tx * 4 + 2] = v.z;
    tile[r][tx * 4 + 3] = v.w;
  }
  __syncthreads();
#pragma unroll
  for (int p = 0; p < 4; ++p) {
    int cc = ty + p * 16;
    u16x4 o;
    o[0] = bf16_bits(tile[tx * 4 + 0][cc]);
    o[1] = bf16_bits(tile[tx * 4 + 1][cc]);
    o[2] = bf16_bits(tile[tx * 4 + 2][cc]);
    o[3] = bf16_bits(tile[tx * 4 + 3][cc]);
    *(u16x4*)(out + (size_t)(c0 + cc) * R + r0 + tx * 4) = o;
  }
}

// ---------------------------------------------------------------- QKV GEMM
// 128x128 tile (r11-verified, unchanged).
__global__ __launch_bounds__(256) void gemm_qkv_kernel(
    const __bf16* __restrict__ A, const __bf16* __restrict__ BT,
    __bf16* __restrict__ Qb, __bf16* __restrict__ Kb, __bf16* __restrict__ VTb) {
  __shared__ __align__(16) __bf16 Asm[128 * 32];
  __shared__ __align__(16) __bf16 Bsm[128 * 32];
  const int KD = 1024;
  int t = threadIdx.x;
  int w = t >> 6, ln = t & 63;
  int wr = w >> 1, wc = w & 1;
  int m0 = blockIdx.y * 128, n0 = blockIdx.x * 128;
  f32x4 acc[4][4] = {};

  int srow = w * 16 + (ln >> 2);
  int scol = (ln & 3) * 8;
  int lrow = ln & 15;
  int lkb = (ln >> 4) * 16;

  for (int kk = 0; kk < KD; kk += 32) {
    __syncthreads();
#pragma unroll
    for (int i = 0; i < 2; ++i) {
      int row = i * 64 + srow;
      gl_lds16(A + (size_t)(m0 + row) * KD + kk + scol,
               (char*)Asm + i * 4096 + w * 1024);
      gl_lds16(BT + (size_t)(n0 + row) * KD + kk + scol,
               (char*)Bsm + i * 4096 + w * 1024);
    }
    __syncthreads();
    bf16x8 af[4], bfr[4];
#pragma unroll
    for (int mi = 0; mi < 4; ++mi)
      af[mi] = *(const bf16x8*)((char*)Asm + (wr * 64 + mi * 16 + lrow) * 64 + lkb);
#pragma unroll
    for (int ni = 0; ni < 4; ++ni)
      bfr[ni] = *(const bf16x8*)((char*)Bsm + (wc * 64 + ni * 16 + lrow) * 64 + lkb);
#pragma unroll
    for (int mi = 0; mi < 4; ++mi)
#pragma unroll
      for (int ni = 0; ni < 4; ++ni)
        acc[mi][ni] = mfma16x16(af[mi], bfr[ni], acc[mi][ni]);
  }

  int r4 = (ln >> 4) * 4;
#pragma unroll
  for (int mi = 0; mi < 4; ++mi) {
#pragma unroll
    for (int ni = 0; ni < 4; ++ni) {
      int grow = m0 + wr * 64 + mi * 16 + r4;
      int gcol = n0 + wc * 64 + ni * 16 + lrow;
      int sel = gcol >> 10;
      int nl = gcol & 1023;
      int h = nl >> 6, d = nl & 63;
      int b = grow >> 11, seq = grow & 2047;
      int bh = b * 16 + h;
      if (sel < 2) {
        __bf16* dst = (sel == 0 ? Qb : Kb) + ((size_t)bh * 2048 + seq) * 64 + d;
#pragma unroll
        for (int r = 0; r < 4; ++r) dst[(size_t)r * 64] = (__bf16)acc[mi][ni][r];
      } else {
        u16x4 o;
        o[0] = bf16_bits(acc[mi][ni][0]);
        o[1] = bf16_bits(acc[mi][ni][1]);
        o[2] = bf16_bits(acc[mi][ni][2]);
        o[3] = bf16_bits(acc[mi][ni][3]);
        *(u16x4*)(VTb + ((size_t)bh * 64 + d) * 2048 + seq) = o;
      }
    }
  }
}

// ---------------------------------------------------------------- out GEMM
// Round-12: BM=128 x BN=64 tile -> grid (16,32) = 512 blocks = 2/CU (was
// 256 = 1/CU: no cross-block overlap to hide the barrier drain). 4 waves
// stacked in M; wave tile 32x64 = acc[2][4]. Same staging/frag algebra.
__global__ __launch_bounds__(256) void gemm_out_kernel(
    const __bf16* __restrict__ A, const __bf16* __restrict__ BT,
    float* __restrict__ Cout, const float* __restrict__ bias) {
  __shared__ __align__(16) __bf16 Asm[128 * 32];  // 8KB
  __shared__ __align__(16) __bf16 Bsm[64 * 32];   // 4KB
  const int KD = 1024;
  int t = threadIdx.x;
  int w = t >> 6, ln = t & 63;
  int m0 = blockIdx.y * 128, n0 = blockIdx.x * 64;
  f32x4 acc[2][4] = {};

  int srow = w * 16 + (ln >> 2);  // 0..63
  int scol = (ln & 3) * 8;
  int lrow = ln & 15;
  int lkb = (ln >> 4) * 16;

  for (int kk = 0; kk < KD; kk += 32) {
    __syncthreads();
#pragma unroll
    for (int i = 0; i < 2; ++i)
      gl_lds16(A + (size_t)(m0 + i * 64 + srow) * KD + kk + scol,
               (char*)Asm + i * 4096 + w * 1024);
    gl_lds16(BT + (size_t)(n0 + srow) * KD + kk + scol, (char*)Bsm + w * 1024);
    __syncthreads();
    bf16x8 af[2], bfr[4];
#pragma unroll
    for (int mi = 0; mi < 2; ++mi)
      af[mi] = *(const bf16x8*)((char*)Asm + (w * 32 + mi * 16 + lrow) * 64 + lkb);
#pragma unroll
    for (int ni = 0; ni < 4; ++ni)
      bfr[ni] = *(const bf16x8*)((char*)Bsm + (ni * 16 + lrow) * 64 + lkb);
#pragma unroll
    for (int mi = 0; mi < 2; ++mi)
#pragma unroll
      for (int ni = 0; ni < 4; ++ni)
        acc[mi][ni] = mfma16x16(af[mi], bfr[ni], acc[mi][ni]);
  }

  int r4 = (ln >> 4) * 4;
#pragma unroll
  for (int mi = 0; mi < 2; ++mi) {
#pragma unroll
    for (int ni = 0; ni < 4; ++ni) {
      int grow = m0 + w * 32 + mi * 16 + r4;
      int gcol = n0 + ni * 16 + lrow;
      float bv = bias[gcol];
#pragma unroll
      for (int r = 0; r < 4; ++r)
        Cout[(size_t)(grow + r) * 1024 + gcol] = acc[mi][ni][r] + bv;
    }
  }
}

// ---------------------------------------------------------------- attention
// r11-verified: j-SPLIT flash (exact under no-max softmax), grid (16,32,2).
__global__ __launch_bounds__(256, 2) void attn_kernel(
    const __bf16* __restrict__ Qb, const __bf16* __restrict__ Kb,
    const __bf16* __restrict__ VTb, __bf16* __restrict__ Opart,
    float* __restrict__ lbuf) {
  __shared__ __align__(16) char Klds[16384];   // 2 bufs x [64 j][128B], swizzled
  __shared__ __align__(16) char Vlds[16384];   // 2 bufs x [64 d][128B], swizzled
  const float LOG2E = 1.44269504f;
  const float K1 = 0.125f * LOG2E;
  int t = threadIdx.x, w = t >> 6, ln = t & 63;
  int hi = ln >> 5, col = ln & 31;
  int bh = blockIdx.y, bq = bh >> 4, h = bh & 15;
  int q0 = blockIdx.x * 128;
  int jh = blockIdx.z;                 // j-half: tiles jh*16 .. jh*16+15
  const __bf16* Qh = Qb + (size_t)bh * 2048 * 64;
  const __bf16* Kh = Kb + (size_t)bh * 2048 * 64;
  const __bf16* Vh = VTb + (size_t)bh * 64 * 2048;
  __bf16* Oh = Opart + (size_t)jh * 4096 * 1024;  // half = 4M bf16 = 8MB

  bf16x8 qf[4];
  int qrow = q0 + w * 32 + col;
#pragma unroll
  for (int dk = 0; dk < 4; ++dk)
    qf[dk] = *(const bf16x8*)(Qh + (size_t)qrow * 64 + dk * 16 + hi * 8);

  f32x16 oacc0 = {}, oacc1 = {};
  float l_run = 0.f;

  int sj0 = t >> 3, sc0 = (t & 7) ^ (sj0 & 7);
  int sj1 = 32 + (t >> 3), sc1 = (t & 7) ^ (sj1 & 7);

#define STAGE(off, j0_)                                                        \
  do {                                                                         \
    gl_lds16(Kh + (size_t)((j0_) + sj0) * 64 + sc0 * 8, Klds + (off) + w * 1024); \
    gl_lds16(Kh + (size_t)((j0_) + sj1) * 64 + sc1 * 8,                        \
             Klds + (off) + 4096 + w * 1024);                                  \
    gl_lds16(Vh + (size_t)sj0 * 2048 + (j0_) + sc0 * 8, Vlds + (off) + w * 1024); \
    gl_lds16(Vh + (size_t)sj1 * 2048 + (j0_) + sc1 * 8,                        \
             Vlds + (off) + 4096 + w * 1024);                                  \
  } while (0)

  int jbase = jh * 16;
  int cur = 0;
  STAGE(0, jbase * 64);
  WAITVM0;
  __builtin_amdgcn_s_barrier();
  __builtin_amdgcn_sched_barrier(0);

  for (int jt = 0; jt < 16; ++jt) {
    if (jt < 15) STAGE((cur ^ 1) * 8192, (jbase + jt + 1) * 64);
    const char* Kc = Klds + cur * 8192;
    const char* Vc = Vlds + cur * 8192;

    f32x16 sfr0 = {}, sfr1 = {};
#pragma unroll
    for (int dk = 0; dk < 4; ++dk) {
      int sw = ((dk * 32 + hi * 16) ^ ((col & 7) << 4));
      bf16x8 kf0 = *(const bf16x8*)(Kc + col * 128 + sw);
      bf16x8 kf1 = *(const bf16x8*)(Kc + (32 + col) * 128 + sw);
      sfr0 = mfma32(kf0, qf[dk], sfr0);
      sfr1 = mfma32(kf1, qf[dk], sfr1);
    }

    float psum = 0.f;
    bf16x8 pfr[4];
#pragma unroll
    for (int jk = 0; jk < 4; ++jk) {
      float p[8];
#pragma unroll
      for (int c = 0; c < 8; ++c) {
        float sv = (jk < 2) ? sfr0[(jk & 1) * 8 + c] : sfr1[(jk & 1) * 8 + c];
        p[c] = __builtin_amdgcn_exp2f(sv * K1);
      }
      psum += ((p[0] + p[1]) + (p[2] + p[3])) + ((p[4] + p[5]) + (p[6] + p[7]));
      unsigned X0 = cvtpk_bf16(p[0], p[1]);
      unsigned X1 = cvtpk_bf16(p[2], p[3]);
      unsigned Y0 = cvtpk_bf16(p[4], p[5]);
      unsigned Y1 = cvtpk_bf16(p[6], p[7]);
      pl32swap(X0, Y0);
      pl32swap(X1, Y1);
      union { unsigned u[4]; bf16x8 v; } pu;
      pu.u[0] = X0; pu.u[1] = X1; pu.u[2] = Y0; pu.u[3] = Y1;
      pfr[jk] = pu.v;
    }
    l_run += psum;

#pragma unroll
    for (int jk = 0; jk < 4; ++jk) {
      int sw = ((jk * 32 + hi * 16) ^ ((col & 7) << 4));
      bf16x8 vf0 = *(const bf16x8*)(Vc + col * 128 + sw);
      bf16x8 vf1 = *(const bf16x8*)(Vc + (32 + col) * 128 + sw);
      oacc0 = mfma32(vf0, pfr[jk], oacc0);
      oacc1 = mfma32(vf1, pfr[jk], oacc1);
    }

    WAITVM0;
    __builtin_amdgcn_s_barrier();
    __builtin_amdgcn_sched_barrier(0);
    cur ^= 1;
  }
#undef STAGE

  l_run += __shfl_xor(l_run, 32);
  float linv = 1.0f / l_run;
  if (hi == 0)
    lbuf[(((size_t)bh * 16 + blockIdx.x) * 2 + jh) * 128 + w * 32 + col] = l_run;

  char* Ow = Klds + w * 4096;  // [32 i][128B d-row], swizzled
#pragma unroll
  for (int da = 0; da < 2; ++da) {
    const f32x16& oa = da ? oacc1 : oacc0;
#pragma unroll
    for (int g = 0; g < 4; ++g) {
      unsigned w0 = cvtpk_bf16(oa[g * 4 + 0] * linv, oa[g * 4 + 1] * linv);
      unsigned w1 = cvtpk_bf16(oa[g * 4 + 2] * linv, oa[g * 4 + 3] * linv);
      int dby = da * 64 + g * 16 + hi * 8;
      char* dst = Ow + col * 128 + ((dby & ~15) ^ ((col & 7) << 4)) + (dby & 8);
      u32x2 pr = {w0, w1};
      *(u32x2*)dst = pr;
    }
  }
  int rr0 = ln >> 3, c16o = ln & 7;
#pragma unroll
  for (int pp = 0; pp < 4; ++pp) {
    int rr = rr0 + pp * 8;
    bf16x8 ov = *(const bf16x8*)(Ow + rr * 128 + ((c16o * 16) ^ ((rr & 7) << 4)));
    int grow = bq * 2048 + q0 + w * 32 + rr;
    *(bf16x8*)(Oh + (size_t)grow * 1024 + h * 64 + c16o * 8) = ov;
  }
}

// ------------------------------------------------------------- combine
// Round-12: vectorized — 8 elems (16B)/thread, grid 2048x256.
__global__ __launch_bounds__(256) void combine_kernel(
    __bf16* __restrict__ O0, const __bf16* __restrict__ O1,
    const float* __restrict__ lbuf) {
  int idx = blockIdx.x * 256 + threadIdx.x;
  int e0 = idx * 8;
  int r = e0 >> 10, c0 = e0 & 1023;
  int b = r >> 11, seq = r & 2047, qb = seq >> 7, i = seq & 127;
  int h = c0 >> 6;  // 8-elem span lies within one head (c0 % 8 == 0)
  int bh = b * 16 + h;
  size_t lbase = (((size_t)bh * 16 + qb) * 2) * 128 + i;
  float l0 = lbuf[lbase], l1 = lbuf[lbase + 128];
  float inv = 1.0f / (l0 + l1);
  float w0 = l0 * inv, w1 = l1 * inv;
  bf16x8 a = *(const bf16x8*)(O0 + e0);
  bf16x8 bb = *(const bf16x8*)(O1 + e0);
  unsigned u[4];
#pragma unroll
  for (int j = 0; j < 4; ++j) {
    float lo = w0 * bf16_f32(a[2 * j]) + w1 * bf16_f32(bb[2 * j]);
    float hi2 = w0 * bf16_f32(a[2 * j + 1]) + w1 * bf16_f32(bb[2 * j + 1]);
    u[j] = cvtpk_bf16(lo, hi2);
  }
  union { unsigned uu[4]; bf16x8 v; } pu;
  pu.uu[0] = u[0]; pu.uu[1] = u[1]; pu.uu[2] = u[2]; pu.uu[3] = u[3];
  *(bf16x8*)(O0 + e0) = pu.v;
}

// ---------------------------------------------------------------- launch
extern "C" void kernel_launch(void* const* d_in, const int* in_sizes, int n_in,
                              void* d_out, int out_size, void* d_ws, size_t ws_size,
                              hipStream_t stream) {
  const float* x = (const float*)d_in[0];
  const float* gamma = (const float*)d_in[1];
  const float* beta = (const float*)d_in[2];
  const float* w_qkv = (const float*)d_in[3];
  const float* w_out = (const float*)d_in[4];
  const float* b_out = (const float*)d_in[5];

  char* ws = (char*)d_ws;
  // [0..8): xn / attn half-0 partial / final sa (in-place combine)
  // [8..16): attn half-1 partial
  // [16..22): wqkvT (dead after QKV GEMM; first 1MB reused as lbuf by attn)
  // [22..24): woutT
  // [24..32): Qb   [32..40): Kb   [40..48): VTb
  __bf16* xn = (__bf16*)(ws);
  __bf16* Opart = xn;                               // halves at +0MB / +8MB
  float* lbuf = (float*)(ws + (16l << 20));
  __bf16* wqkvT = (__bf16*)(ws + (16l << 20));
  __bf16* woutT = (__bf16*)(ws + (22l << 20));
  __bf16* Qb = (__bf16*)(ws + (24l << 20));
  __bf16* Kb = (__bf16*)(ws + (32l << 20));
  __bf16* VTb = (__bf16*)(ws + (40l << 20));
  __bf16* sa = xn;  // combine merges half-1 into half-0 in place

  ln_kernel<<<4096, 256, 0, stream>>>(x, gamma, beta, xn);
  transpose_bf16_kernel<<<dim3(48, 16), 256, 0, stream>>>(w_qkv, wqkvT, 1024, 3072);
  transpose_bf16_kernel<<<dim3(16, 16), 256, 0, stream>>>(w_out, woutT, 1024, 1024);
  gemm_qkv_kernel<<<dim3(24, 32), 256, 0, stream>>>(xn, wqkvT, Qb, Kb, VTb);
  attn_kernel<<<dim3(16, 32, 2), 256, 0, stream>>>(Qb, Kb, VTb, Opart, lbuf);
  combine_kernel<<<2048, 256, 0, stream>>>(sa, Opart + (4096l * 1024), lbuf);
  gemm_out_kernel<<<dim3(16, 32), 256, 0, stream>>>(sa, woutT, (float*)d_out, b_out);
}